// Round 6
// baseline (167.249 us; speedup 1.0000x reference)
//
#include <hip/hip_runtime.h>
#include <math.h>

#define NTHR 256
#define CF   4                       // frames walked per thread
#define NBLK (4 * (512 / CF) * 4)    // B * F/CF * quarters = 2048
#define B_ 4
#define F_ 512
#define N_ 1024
#define V_ 4

struct Partial {                     // 64 B, all f32
  float sum_diff2, sum_dist, sum_acc2, cnt;
  float gmin[3], gmax[3], pmin[3], pmax[3];
};

__global__ __launch_bounds__(NTHR, 6) void loss_main(
    const float* __restrict__ pred, const float* __restrict__ gt,
    const int* __restrict__ vis, const float* __restrict__ P,
    const float* __restrict__ tracks, Partial* __restrict__ partials)
{
  __shared__ float sP[V_ * 12];
  __shared__ Partial sw[NTHR / 64];

  const int bid = blockIdx.x;
  const int b  = bid >> 9;                  // 512 blocks per batch
  const int fc = (bid >> 2) & 127;          // frame chunk (CF frames)
  const int qr = bid & 3;                   // quarter of N row
  const int f0 = fc << 2;
  const int t  = threadIdx.x;
  const int n  = (qr << 8) + t;             // this thread's point

  if (t < V_ * 12) {
    const int v = t / 12, j = t - v * 12;
    sP[t] = P[(v * B_ + b) * 12 + j];
  }
  __syncthreads();

  // sliding pred window: rows f0, f0+1 in registers
  const size_t colOff = (size_t)n * 3;
  const float* pr0 = pred + ((size_t)(b * F_ + f0) * N_) * 3 + colOff;
  float p0x = pr0[0], p0y = pr0[1], p0z = pr0[2];
  const float* pr1 = pred + ((size_t)(b * F_ + f0 + 1) * N_) * 3 + colOff;
  float p1x = pr1[0], p1y = pr1[1], p1z = pr1[2];

  float sum_diff2 = 0.0f, sum_dist = 0.0f, sum_acc2 = 0.0f, cntf = 0.0f;
  float gmin[3] = { INFINITY,  INFINITY,  INFINITY};
  float gmax[3] = {-INFINITY, -INFINITY, -INFINITY};
  float pmin[3] = { INFINITY,  INFINITY,  INFINITY};
  float pmax[3] = {-INFINITY, -INFINITY, -INFINITY};

#pragma unroll
  for (int i = 0; i < CF; ++i) {
    const int fi = f0 + i;
    const int r2 = (fi + 2 < F_) ? fi + 2 : F_ - 1;   // clamped (acc guarded)

    // ---- loads for this frame (all coalesced across lanes)
    const float* p2p = pred + ((size_t)(b * F_ + r2) * N_) * 3 + colOff;
    const float p2x = p2p[0], p2y = p2p[1], p2z = p2p[2];

    const float* gp = gt + ((size_t)(b * F_ + fi) * N_) * 3 + colOff;
    const float gx = gp[0], gy = gp[1], gz = gp[2];

    const int vm = vis[(size_t)(b * F_ + fi) * N_ + n];

    const float2 tk0 = *(const float2*)(tracks + (((size_t)(0 * B_ + b) * F_ + fi) * N_ + n) * 2);
    const float2 tk1 = *(const float2*)(tracks + (((size_t)(1 * B_ + b) * F_ + fi) * N_ + n) * 2);
    const float2 tk2 = *(const float2*)(tracks + (((size_t)(2 * B_ + b) * F_ + fi) * N_ + n) * 2);
    const float2 tk3 = *(const float2*)(tracks + (((size_t)(3 * B_ + b) * F_ + fi) * N_ + n) * 2);

    // ---- current point is the window head (p0)
    const float px = p0x, py = p0y, pz = p0z;

    pmin[0] = fminf(pmin[0], px); pmax[0] = fmaxf(pmax[0], px);
    pmin[1] = fminf(pmin[1], py); pmax[1] = fmaxf(pmax[1], py);
    pmin[2] = fminf(pmin[2], pz); pmax[2] = fmaxf(pmax[2], pz);

    if (vm) {
      const float d0 = px - gx, d1 = py - gy, d2 = pz - gz;
      sum_diff2 += d0 * d0 + d1 * d1 + d2 * d2;
      cntf += 1.0f;
      gmin[0] = fminf(gmin[0], gx); gmax[0] = fmaxf(gmax[0], gx);
      gmin[1] = fminf(gmin[1], gy); gmax[1] = fmaxf(gmax[1], gy);
      gmin[2] = fminf(gmin[2], gz); gmax[2] = fmaxf(gmax[2], gz);
    }

    if (fi < F_ - 2) {
      const float a0 = p2x - 2.0f * p1x + px;
      const float a1 = p2y - 2.0f * p1y + py;
      const float a2 = p2z - 2.0f * p1z + pz;
      sum_acc2 += a0 * a0 + a1 * a1 + a2 * a2;
    }

    const float2 tks[V_] = {tk0, tk1, tk2, tk3};
#pragma unroll
    for (int v = 0; v < V_; ++v) {
      const float* Pm = sP + v * 12;
      const float a0 = Pm[0] * px + Pm[1] * py + Pm[2]  * pz + Pm[3];
      const float a1 = Pm[4] * px + Pm[5] * py + Pm[6]  * pz + Pm[7];
      const float a2 = Pm[8] * px + Pm[9] * py + Pm[10] * pz + Pm[11];
      const float inv = 1.0f / (a2 + 1e-10f);
      const float dx = a0 * inv - tks[v].x;
      const float dy = a1 * inv - tks[v].y;
      sum_dist += dx * dx + dy * dy;
    }

    // ---- slide window
    p0x = p1x; p0y = p1y; p0z = p1z;
    p1x = p2x; p1y = p2y; p1z = p2z;
  }

  // ---------------- wave shuffle reduction (f32, deterministic tree)
#pragma unroll
  for (int o = 32; o > 0; o >>= 1) {
    sum_diff2 += __shfl_down(sum_diff2, o);
    sum_dist  += __shfl_down(sum_dist,  o);
    sum_acc2  += __shfl_down(sum_acc2,  o);
    cntf      += __shfl_down(cntf,      o);
#pragma unroll
    for (int k = 0; k < 3; ++k) {
      gmin[k] = fminf(gmin[k], __shfl_down(gmin[k], o));
      gmax[k] = fmaxf(gmax[k], __shfl_down(gmax[k], o));
      pmin[k] = fminf(pmin[k], __shfl_down(pmin[k], o));
      pmax[k] = fmaxf(pmax[k], __shfl_down(pmax[k], o));
    }
  }

  const int wave = t >> 6, lane = t & 63;
  if (lane == 0) {
    Partial p;
    p.sum_diff2 = sum_diff2; p.sum_dist = sum_dist;
    p.sum_acc2  = sum_acc2;  p.cnt      = cntf;
#pragma unroll
    for (int k = 0; k < 3; ++k) {
      p.gmin[k] = gmin[k]; p.gmax[k] = gmax[k];
      p.pmin[k] = pmin[k]; p.pmax[k] = pmax[k];
    }
    sw[wave] = p;
  }
  __syncthreads();
  if (t == 0) {
    Partial p = sw[0];
#pragma unroll
    for (int w = 1; w < NTHR / 64; ++w) {
      p.sum_diff2 += sw[w].sum_diff2; p.sum_dist += sw[w].sum_dist;
      p.sum_acc2  += sw[w].sum_acc2;  p.cnt      += sw[w].cnt;
#pragma unroll
      for (int k = 0; k < 3; ++k) {
        p.gmin[k] = fminf(p.gmin[k], sw[w].gmin[k]);
        p.gmax[k] = fmaxf(p.gmax[k], sw[w].gmax[k]);
        p.pmin[k] = fminf(p.pmin[k], sw[w].pmin[k]);
        p.pmax[k] = fmaxf(p.pmax[k], sw[w].pmax[k]);
      }
    }
    partials[bid] = p;
  }
}

__global__ __launch_bounds__(NTHR) void loss_final(
    const Partial* __restrict__ partials, float* __restrict__ out)
{
  float sum_diff2 = 0.0f, sum_dist = 0.0f, sum_acc2 = 0.0f, cnt = 0.0f;
  float gmin[3] = { INFINITY,  INFINITY,  INFINITY};
  float gmax[3] = {-INFINITY, -INFINITY, -INFINITY};
  float pmin[3] = { INFINITY,  INFINITY,  INFINITY};
  float pmax[3] = {-INFINITY, -INFINITY, -INFINITY};

  const int tid = threadIdx.x;
  for (int i = tid; i < NBLK; i += NTHR) {   // fixed order -> deterministic
    const Partial p = partials[i];
    sum_diff2 += p.sum_diff2; sum_dist += p.sum_dist;
    sum_acc2  += p.sum_acc2;  cnt      += p.cnt;
#pragma unroll
    for (int k = 0; k < 3; ++k) {
      gmin[k] = fminf(gmin[k], p.gmin[k]); gmax[k] = fmaxf(gmax[k], p.gmax[k]);
      pmin[k] = fminf(pmin[k], p.pmin[k]); pmax[k] = fmaxf(pmax[k], p.pmax[k]);
    }
  }

#pragma unroll
  for (int o = 32; o > 0; o >>= 1) {
    sum_diff2 += __shfl_down(sum_diff2, o);
    sum_dist  += __shfl_down(sum_dist,  o);
    sum_acc2  += __shfl_down(sum_acc2,  o);
    cnt       += __shfl_down(cnt,       o);
#pragma unroll
    for (int k = 0; k < 3; ++k) {
      gmin[k] = fminf(gmin[k], __shfl_down(gmin[k], o));
      gmax[k] = fmaxf(gmax[k], __shfl_down(gmax[k], o));
      pmin[k] = fminf(pmin[k], __shfl_down(pmin[k], o));
      pmax[k] = fmaxf(pmax[k], __shfl_down(pmax[k], o));
    }
  }

  __shared__ Partial sw[NTHR / 64];
  const int lane = tid & 63;
  const int wave = tid >> 6;
  if (lane == 0) {
    Partial p;
    p.sum_diff2 = sum_diff2; p.sum_dist = sum_dist;
    p.sum_acc2  = sum_acc2;  p.cnt      = cnt;
#pragma unroll
    for (int k = 0; k < 3; ++k) {
      p.gmin[k] = gmin[k]; p.gmax[k] = gmax[k];
      p.pmin[k] = pmin[k]; p.pmax[k] = pmax[k];
    }
    sw[wave] = p;
  }
  __syncthreads();

  if (tid == 0) {
    Partial p = sw[0];
#pragma unroll
    for (int w = 1; w < NTHR / 64; ++w) {
      p.sum_diff2 += sw[w].sum_diff2; p.sum_dist += sw[w].sum_dist;
      p.sum_acc2  += sw[w].sum_acc2;  p.cnt      += sw[w].cnt;
#pragma unroll
      for (int k = 0; k < 3; ++k) {
        p.gmin[k] = fminf(p.gmin[k], sw[w].gmin[k]);
        p.gmax[k] = fmaxf(p.gmax[k], sw[w].gmax[k]);
        p.pmin[k] = fminf(p.pmin[k], sw[w].pmin[k]);
        p.pmax[k] = fmaxf(p.pmax[k], sw[w].pmax[k]);
      }
    }

    double sr = -INFINITY;
#pragma unroll
    for (int k = 0; k < 3; ++k) sr = fmax(sr, (double)p.gmax[k] - (double)p.gmin[k]);
    sr += 1e-6;
    const double recon = (double)p.sum_diff2 / fmax((double)p.cnt * 3.0, 1.0) / (sr * sr);

    const double ident = (double)p.sum_dist / 224.0 / ((double)V_ * B_ * F_ * N_ * 2.0);

    double st = -INFINITY;
#pragma unroll
    for (int k = 0; k < 3; ++k) st = fmax(st, (double)p.pmax[k] - (double)p.pmin[k]);
    st += 1e-6;
    const double tloss = (double)p.sum_acc2 / ((double)B_ * (F_ - 2) * N_);
    const double temp = tloss / (st * st);

    const double total = recon + ident + 0.5 * temp;
    out[0] = (float)total;
    out[1] = (float)recon;
    out[2] = (float)ident;
    out[3] = (float)temp;
  }
}

extern "C" void kernel_launch(void* const* d_in, const int* in_sizes, int n_in,
                              void* d_out, int out_size, void* d_ws, size_t ws_size,
                              hipStream_t stream) {
  const float* pred   = (const float*)d_in[0];
  const float* gt     = (const float*)d_in[1];
  const int*   vis    = (const int*)d_in[2];
  const float* P      = (const float*)d_in[3];
  const float* tracks = (const float*)d_in[4];
  float* out = (float*)d_out;
  Partial* partials = (Partial*)d_ws;

  loss_main<<<NBLK, NTHR, 0, stream>>>(pred, gt, vis, P, tracks, partials);
  loss_final<<<1, NTHR, 0, stream>>>(partials, out);
}

// Round 7
// 56.812 us; speedup vs baseline: 2.9439x; 2.9439x over previous
//
#include <hip/hip_runtime.h>
#include <math.h>

#define NTHR 256
#define B_ 4
#define F_ 512
#define N_ 1024
#define V_ 4
#define NPTS (B_ * F_ * N_)          // 2097152
#define NBLK (NPTS / NTHR)           // 8192
#define NTHRF 1024                   // final-reduce block size

struct Partial {                     // 64 B, all f32
  float sum_diff2, sum_dist, sum_acc2, cnt;
  float gmin[3], gmax[3], pmin[3], pmax[3];
};

__global__ __launch_bounds__(NTHR, 8) void loss_main(
    const float* __restrict__ pred, const float* __restrict__ gt,
    const int* __restrict__ vis, const float* __restrict__ P,
    const float* __restrict__ tracks, Partial* __restrict__ partials)
{
  __shared__ float sP[V_ * 12];
  __shared__ Partial sw[NTHR / 64];

  // XCD-bijective swizzle: 8192 blocks, 8 XCDs -> 1024 consecutive blocks/XCD
  const int bid = ((blockIdx.x & 7) << 10) + (blockIdx.x >> 3);
  const int t = threadIdx.x;
  const int e = (bid << 8) + t;            // point id
  const int b = e >> 19;
  const int f = (e >> 10) & (F_ - 1);
  const int fn = e & ((F_ * N_) - 1);      // f*N + n

  if (t < V_ * 12) {
    const int v = t / 12, j = t - v * 12;
    sP[t] = P[(v * B_ + b) * 12 + j];
  }
  __syncthreads();

  // ================= all loads up front, independent =================
  const float* pp = pred + (size_t)e * 3;
  const float px = pp[0], py = pp[1], pz = pp[2];

  const float* gp = gt + (size_t)e * 3;
  const float gx = gp[0], gy = gp[1], gz = gp[2];

  const int vm = vis[e];

  const int d1 = (f + 1 < F_) ? N_ : 0;    // clamped neighbor offsets (points)
  const int d2 = (f + 2 < F_) ? 2 * N_ : 0;
  const float* q1 = pred + (size_t)(e + d1) * 3;
  const float n1x = q1[0], n1y = q1[1], n1z = q1[2];
  const float* q2 = pred + (size_t)(e + d2) * 3;
  const float n2x = q2[0], n2y = q2[1], n2z = q2[2];

  const float2 tk0 = *(const float2*)(tracks + ((((size_t)(0 * B_ + b) << 19) + fn) << 1));
  const float2 tk1 = *(const float2*)(tracks + ((((size_t)(1 * B_ + b) << 19) + fn) << 1));
  const float2 tk2 = *(const float2*)(tracks + ((((size_t)(2 * B_ + b) << 19) + fn) << 1));
  const float2 tk3 = *(const float2*)(tracks + ((((size_t)(3 * B_ + b) << 19) + fn) << 1));

  // ================= compute (branchless) =================
  const float vmf = vm ? 1.0f : 0.0f;
  const float dd0 = px - gx, dd1 = py - gy, dd2 = pz - gz;
  float sum_diff2 = vmf * (dd0 * dd0 + dd1 * dd1 + dd2 * dd2);
  float cntf = vmf;
  float gmin[3], gmax[3], pmin[3], pmax[3];
  gmin[0] = vm ? gx :  INFINITY; gmax[0] = vm ? gx : -INFINITY;
  gmin[1] = vm ? gy :  INFINITY; gmax[1] = vm ? gy : -INFINITY;
  gmin[2] = vm ? gz :  INFINITY; gmax[2] = vm ? gz : -INFINITY;
  pmin[0] = px; pmax[0] = px;
  pmin[1] = py; pmax[1] = py;
  pmin[2] = pz; pmax[2] = pz;

  const float am = (f < F_ - 2) ? 1.0f : 0.0f;
  const float a0 = n2x - 2.0f * n1x + px;
  const float a1 = n2y - 2.0f * n1y + py;
  const float a2 = n2z - 2.0f * n1z + pz;
  float sum_acc2 = am * (a0 * a0 + a1 * a1 + a2 * a2);

  float sum_dist = 0.0f;
  const float2 tks[V_] = {tk0, tk1, tk2, tk3};
#pragma unroll
  for (int v = 0; v < V_; ++v) {
    const float* Pm = sP + v * 12;
    const float h0 = Pm[0] * px + Pm[1] * py + Pm[2]  * pz + Pm[3];
    const float h1 = Pm[4] * px + Pm[5] * py + Pm[6]  * pz + Pm[7];
    const float h2 = Pm[8] * px + Pm[9] * py + Pm[10] * pz + Pm[11];
    const float inv = __builtin_amdgcn_rcpf(h2 + 1e-10f);
    const float dx = h0 * inv - tks[v].x;
    const float dy = h1 * inv - tks[v].y;
    sum_dist += dx * dx + dy * dy;
  }

  // ================= wave shuffle reduction (deterministic) =================
#pragma unroll
  for (int o = 32; o > 0; o >>= 1) {
    sum_diff2 += __shfl_down(sum_diff2, o);
    sum_dist  += __shfl_down(sum_dist,  o);
    sum_acc2  += __shfl_down(sum_acc2,  o);
    cntf      += __shfl_down(cntf,      o);
#pragma unroll
    for (int k = 0; k < 3; ++k) {
      gmin[k] = fminf(gmin[k], __shfl_down(gmin[k], o));
      gmax[k] = fmaxf(gmax[k], __shfl_down(gmax[k], o));
      pmin[k] = fminf(pmin[k], __shfl_down(pmin[k], o));
      pmax[k] = fmaxf(pmax[k], __shfl_down(pmax[k], o));
    }
  }

  const int wave = t >> 6, lane = t & 63;
  if (lane == 0) {
    Partial p;
    p.sum_diff2 = sum_diff2; p.sum_dist = sum_dist;
    p.sum_acc2  = sum_acc2;  p.cnt      = cntf;
#pragma unroll
    for (int k = 0; k < 3; ++k) {
      p.gmin[k] = gmin[k]; p.gmax[k] = gmax[k];
      p.pmin[k] = pmin[k]; p.pmax[k] = pmax[k];
    }
    sw[wave] = p;
  }
  __syncthreads();
  if (t == 0) {
    Partial p = sw[0];
#pragma unroll
    for (int w = 1; w < NTHR / 64; ++w) {
      p.sum_diff2 += sw[w].sum_diff2; p.sum_dist += sw[w].sum_dist;
      p.sum_acc2  += sw[w].sum_acc2;  p.cnt      += sw[w].cnt;
#pragma unroll
      for (int k = 0; k < 3; ++k) {
        p.gmin[k] = fminf(p.gmin[k], sw[w].gmin[k]);
        p.gmax[k] = fmaxf(p.gmax[k], sw[w].gmax[k]);
        p.pmin[k] = fminf(p.pmin[k], sw[w].pmin[k]);
        p.pmax[k] = fmaxf(p.pmax[k], sw[w].pmax[k]);
      }
    }
    partials[bid] = p;
  }
}

__global__ __launch_bounds__(NTHRF) void loss_final(
    const Partial* __restrict__ partials, float* __restrict__ out)
{
  float sum_diff2 = 0.0f, sum_dist = 0.0f, sum_acc2 = 0.0f, cnt = 0.0f;
  float gmin[3] = { INFINITY,  INFINITY,  INFINITY};
  float gmax[3] = {-INFINITY, -INFINITY, -INFINITY};
  float pmin[3] = { INFINITY,  INFINITY,  INFINITY};
  float pmax[3] = {-INFINITY, -INFINITY, -INFINITY};

  const int tid = threadIdx.x;
  const float4* pf = (const float4*)partials;
  for (int i = tid; i < NBLK; i += NTHRF) {    // fixed order -> deterministic
    const float4 a = pf[i * 4 + 0];
    const float4 bq = pf[i * 4 + 1];
    const float4 c = pf[i * 4 + 2];
    const float4 d = pf[i * 4 + 3];
    sum_diff2 += a.x; sum_dist += a.y; sum_acc2 += a.z; cnt += a.w;
    gmin[0] = fminf(gmin[0], bq.x); gmin[1] = fminf(gmin[1], bq.y);
    gmin[2] = fminf(gmin[2], bq.z); gmax[0] = fmaxf(gmax[0], bq.w);
    gmax[1] = fmaxf(gmax[1], c.x);  gmax[2] = fmaxf(gmax[2], c.y);
    pmin[0] = fminf(pmin[0], c.z);  pmin[1] = fminf(pmin[1], c.w);
    pmin[2] = fminf(pmin[2], d.x);  pmax[0] = fmaxf(pmax[0], d.y);
    pmax[1] = fmaxf(pmax[1], d.z);  pmax[2] = fmaxf(pmax[2], d.w);
  }

#pragma unroll
  for (int o = 32; o > 0; o >>= 1) {
    sum_diff2 += __shfl_down(sum_diff2, o);
    sum_dist  += __shfl_down(sum_dist,  o);
    sum_acc2  += __shfl_down(sum_acc2,  o);
    cnt       += __shfl_down(cnt,       o);
#pragma unroll
    for (int k = 0; k < 3; ++k) {
      gmin[k] = fminf(gmin[k], __shfl_down(gmin[k], o));
      gmax[k] = fmaxf(gmax[k], __shfl_down(gmax[k], o));
      pmin[k] = fminf(pmin[k], __shfl_down(pmin[k], o));
      pmax[k] = fmaxf(pmax[k], __shfl_down(pmax[k], o));
    }
  }

  __shared__ Partial sw[NTHRF / 64];
  const int lane = tid & 63;
  const int wave = tid >> 6;
  if (lane == 0) {
    Partial p;
    p.sum_diff2 = sum_diff2; p.sum_dist = sum_dist;
    p.sum_acc2  = sum_acc2;  p.cnt      = cnt;
#pragma unroll
    for (int k = 0; k < 3; ++k) {
      p.gmin[k] = gmin[k]; p.gmax[k] = gmax[k];
      p.pmin[k] = pmin[k]; p.pmax[k] = pmax[k];
    }
    sw[wave] = p;
  }
  __syncthreads();

  if (tid == 0) {
    Partial p = sw[0];
#pragma unroll
    for (int w = 1; w < NTHRF / 64; ++w) {
      p.sum_diff2 += sw[w].sum_diff2; p.sum_dist += sw[w].sum_dist;
      p.sum_acc2  += sw[w].sum_acc2;  p.cnt      += sw[w].cnt;
#pragma unroll
      for (int k = 0; k < 3; ++k) {
        p.gmin[k] = fminf(p.gmin[k], sw[w].gmin[k]);
        p.gmax[k] = fmaxf(p.gmax[k], sw[w].gmax[k]);
        p.pmin[k] = fminf(p.pmin[k], sw[w].pmin[k]);
        p.pmax[k] = fmaxf(p.pmax[k], sw[w].pmax[k]);
      }
    }

    double sr = -INFINITY;
#pragma unroll
    for (int k = 0; k < 3; ++k) sr = fmax(sr, (double)p.gmax[k] - (double)p.gmin[k]);
    sr += 1e-6;
    const double recon = (double)p.sum_diff2 / fmax((double)p.cnt * 3.0, 1.0) / (sr * sr);

    const double ident = (double)p.sum_dist / 224.0 / ((double)V_ * B_ * F_ * N_ * 2.0);

    double st = -INFINITY;
#pragma unroll
    for (int k = 0; k < 3; ++k) st = fmax(st, (double)p.pmax[k] - (double)p.pmin[k]);
    st += 1e-6;
    const double tloss = (double)p.sum_acc2 / ((double)B_ * (F_ - 2) * N_);
    const double temp = tloss / (st * st);

    const double total = recon + ident + 0.5 * temp;
    out[0] = (float)total;
    out[1] = (float)recon;
    out[2] = (float)ident;
    out[3] = (float)temp;
  }
}

extern "C" void kernel_launch(void* const* d_in, const int* in_sizes, int n_in,
                              void* d_out, int out_size, void* d_ws, size_t ws_size,
                              hipStream_t stream) {
  const float* pred   = (const float*)d_in[0];
  const float* gt     = (const float*)d_in[1];
  const int*   vis    = (const int*)d_in[2];
  const float* P      = (const float*)d_in[3];
  const float* tracks = (const float*)d_in[4];
  float* out = (float*)d_out;
  Partial* partials = (Partial*)d_ws;   // 8192 * 64 B = 512 KB

  loss_main<<<NBLK, NTHR, 0, stream>>>(pred, gt, vis, P, tracks, partials);
  loss_final<<<1, NTHRF, 0, stream>>>(partials, out);
}